// Round 4
// baseline (150.984 us; speedup 1.0000x reference)
//
#include <hip/hip_runtime.h>

#define N 8192
#define D 256
#define INV_TAU 14.285714285714286f
#define SCALE2 20.60992915555662f    // INV_TAU * log2(e)
#define LN2F 0.6931471805599453f
#define EPSN 1e-6f
#define MAXM 128                     // class-size cap (Poisson(8); P(>40) ~ 1e-16)

// fused-lse geometry
#define RT 256            // rows per block (4 waves x 64 rows)
#define CT 64             // cols per LDS tile
#define CSPLIT 16         // column splits across blocks
#define CPB (N / CSPLIT)  // 512 cols per block
#define NTILES (CPB / CT) // 8 tiles

typedef unsigned int u32x4 __attribute__((ext_vector_type(4)));
typedef __bf16 bf16x8 __attribute__((ext_vector_type(8)));
typedef float f32x4 __attribute__((ext_vector_type(4)));

__device__ inline unsigned short f2bf(float x) {
    unsigned int u = __builtin_bit_cast(unsigned int, x);
    u += 0x7fffu + ((u >> 16) & 1u);   // RNE (finite inputs)
    return (unsigned short)(u >> 16);
}
__device__ inline float b2f(unsigned short u) {
    unsigned int x = (unsigned int)u << 16;
    return __builtin_bit_cast(float, x);
}
__device__ inline float fexp2(float x) {
#if __has_builtin(__builtin_amdgcn_exp2f)
    return __builtin_amdgcn_exp2f(x);
#else
    return __expf(x * 0.6931471805599453f);
#endif
}

// One wave per row: normalize -> bf16. A rows are pre-scaled by SCALE2 so the
// GEMM epilogue is exp2(dot) with no multiply. Bm is 16B-chunk XOR-swizzled
// (chunk c of row r stored at c ^ (r&7)) so LDS fragment reads are
// conflict-free while global->LDS staging stays a linear copy.
__global__ void ntx_prep(const float* __restrict__ im, const float* __restrict__ rec,
                         unsigned short* __restrict__ A, unsigned short* __restrict__ Bm,
                         float* __restrict__ diag, float* __restrict__ rowsum,
                         float* __restrict__ acc) {
    const int wave = threadIdx.x >> 6;
    const int lane = threadIdx.x & 63;
    const int row  = blockIdx.x * 4 + wave;

    const float4 a = ((const float4*)(im  + (size_t)row * D))[lane];
    const float4 b = ((const float4*)(rec + (size_t)row * D))[lane];

    float ssa = a.x*a.x + a.y*a.y + a.z*a.z + a.w*a.w;
    float ssb = b.x*b.x + b.y*b.y + b.z*b.z + b.w*b.w;
    float dt  = a.x*b.x + a.y*b.y + a.z*b.z + a.w*b.w;
    #pragma unroll
    for (int o = 32; o; o >>= 1) {
        ssa += __shfl_xor(ssa, o);
        ssb += __shfl_xor(ssb, o);
        dt  += __shfl_xor(dt , o);
    }
    const float ra = SCALE2 / fmaxf(sqrtf(ssa), EPSN);   // scaled into A
    const float rb = 1.0f   / fmaxf(sqrtf(ssb), EPSN);

    ushort4 pa, pb;
    pa.x = f2bf(a.x*ra); pa.y = f2bf(a.y*ra); pa.z = f2bf(a.z*ra); pa.w = f2bf(a.w*ra);
    pb.x = f2bf(b.x*rb); pb.y = f2bf(b.y*rb); pb.z = f2bf(b.z*rb); pb.w = f2bf(b.w*rb);

    *(ushort4*)(A + (size_t)row * D + lane * 4) = pa;
    const int chunk = lane >> 1;
    const int sw = chunk ^ (row & 7);
    *(ushort4*)(Bm + (size_t)row * D + sw * 8 + (lane & 1) * 4) = pb;

    if (lane == 0) {
        diag[row]   = (dt / SCALE2) * ra * rb * INV_TAU;  // fp32 i2r[i,i], unscaled
        rowsum[row] = 0.0f;                               // ws is poisoned each launch
        if (row == 0) acc[0] = 0.0f;
    }
}

// Fused GEMM + UNMASKED sum-of-exp2 per row. 512 blocks x 256 threads.
// Double-buffered LDS: barrier drains tile t, then stage(t+1) is issued and
// its vmcnt drain overlaps the full compute of tile t.
__global__ __launch_bounds__(256, 2)
void ntx_lse(const unsigned short* __restrict__ A, const unsigned short* __restrict__ Bm,
             float* __restrict__ rowsum) {
    __shared__ __align__(16) unsigned short Bs[2][CT][D];   // 64 KB

    const int wave = threadIdx.x >> 6;
    const int lane = threadIdx.x & 63;
    const int g    = lane >> 4;
    const int n16  = lane & 15;

    const int rowblk = blockIdx.x & (N / RT - 1);   // 0..31
    const int colblk = blockIdx.x >> 5;             // 0..15
    const int row0 = rowblk * RT + wave * 64;       // this wave's 64 rows
    const int col0 = colblk * CPB;

    // A fragments: 64 rows x K=256 in registers (128 VGPRs)
    bf16x8 afrag[4][8];
    #pragma unroll
    for (int rs = 0; rs < 4; ++rs) {
        const int r = row0 + rs * 16 + n16;
        #pragma unroll
        for (int k = 0; k < 8; ++k)
            afrag[rs][k] = __builtin_bit_cast(
                bf16x8, *(const u32x4*)(A + (size_t)r * D + k * 32 + g * 8));
    }

    float acc[4][4];
    #pragma unroll
    for (int rs = 0; rs < 4; ++rs)
        #pragma unroll
        for (int q = 0; q < 4; ++q) acc[rs][q] = 0.f;

    const char* gbase = (const char*)(Bm + (size_t)col0 * D);

    // stage tile t into buffer buf (32 KB linear copy, 1 KB per instr)
    #define STAGE(t, buf)                                                          \
        {                                                                          \
            const char* gsrc = gbase + (t) * (CT * D * 2);                         \
            char* lbase = (char*)&Bs[buf][0][0];                                   \
            _Pragma("unroll")                                                      \
            for (int i = 0; i < 8; ++i) {                                          \
                const int off = (i * 4 + wave) * 1024;                             \
                __builtin_amdgcn_global_load_lds(                                  \
                    (const __attribute__((address_space(1))) void*)(gsrc + off + lane * 16), \
                    (__attribute__((address_space(3))) void*)(lbase + off),        \
                    16, 0, 0);                                                     \
            }                                                                      \
        }

    STAGE(0, 0)

    for (int t = 0; t < NTILES; ++t) {
        __syncthreads();                    // drains stage(t) (vmcnt 0 at barrier)
        if (t + 1 < NTILES) STAGE(t + 1, (t + 1) & 1)
        const int buf = t & 1;

        #pragma unroll
        for (int cs = 0; cs < 4; ++cs) {
            const int bc = cs * 16 + n16;
            bf16x8 bfrag[8];
            #pragma unroll
            for (int k = 0; k < 8; ++k)
                bfrag[k] = __builtin_bit_cast(
                    bf16x8, *(const u32x4*)(&Bs[buf][bc][((k * 4 + g) ^ (bc & 7)) * 8]));

            #pragma unroll
            for (int rs = 0; rs < 4; ++rs) {
                f32x4 c = {0.f, 0.f, 0.f, 0.f};
                #pragma unroll
                for (int k = 0; k < 8; ++k)
                    c = __builtin_amdgcn_mfma_f32_16x16x32_bf16(
                            afrag[rs][k], bfrag[k], c, 0, 0, 0);
                #pragma unroll
                for (int q = 0; q < 4; ++q)
                    acc[rs][q] += fexp2(c[q]);   // A pre-scaled: no mul, no mask
            }
        }
    }

    #pragma unroll
    for (int rs = 0; rs < 4; ++rs)
        #pragma unroll
        for (int q = 0; q < 4; ++q) {
            float v = acc[rs][q];
            v += __shfl_xor(v, 1);
            v += __shfl_xor(v, 2);
            v += __shfl_xor(v, 4);
            v += __shfl_xor(v, 8);
            if (n16 == 0)
                atomicAdd(&rowsum[row0 + rs * 16 + g * 4 + q], v);
        }
}

// Block per class: find members by scanning labels, subtract same-label
// off-diagonal exps from rowsum, and fold the final loss reduction in:
// acc += sum over rows of (ln(rowsum - corr) - diag).
__global__ void ntx_ccf(const unsigned short* __restrict__ A,
                        const unsigned short* __restrict__ Bm,
                        const int* __restrict__ labels,
                        const float* __restrict__ diag,
                        const float* __restrict__ rowsum,
                        float* __restrict__ acc) {
    __shared__ int   rows[MAXM];
    __shared__ float corr[MAXM];
    __shared__ int   mcnt;
    __shared__ float wred[4];

    const int c = blockIdx.x;
    if (threadIdx.x == 0) mcnt = 0;
    __syncthreads();

    for (int i = threadIdx.x; i < N; i += 256)
        if (labels[i] == c) {
            const int u = atomicAdd(&mcnt, 1);
            if (u < MAXM) rows[u] = i;
        }
    __syncthreads();
    const int m = min(mcnt, MAXM);
    for (int i = threadIdx.x; i < m; i += 256) corr[i] = 0.f;
    __syncthreads();

    const int wave = threadIdx.x >> 6;
    const int lane = threadIdx.x & 63;
    const int chunk = lane >> 1;

    // one wave per (i,j) pair, full-wave 256-elem dot + shuffle reduce
    for (int p = wave; p < m * m; p += 4) {
        const int i = p / m, j = p - i * m;
        if (i == j) continue;
        const int r  = rows[i];
        const int jr = rows[j];
        const ushort4 av = *(const ushort4*)(A + (size_t)r * D + lane * 4);
        const int sw = chunk ^ (jr & 7);   // unswizzle Bm row jr
        const ushort4 bv = *(const ushort4*)(Bm + (size_t)jr * D + sw * 8 + (lane & 1) * 4);
        float d = b2f(av.x)*b2f(bv.x) + b2f(av.y)*b2f(bv.y)
                + b2f(av.z)*b2f(bv.z) + b2f(av.w)*b2f(bv.w);
        #pragma unroll
        for (int o = 32; o; o >>= 1) d += __shfl_xor(d, o);
        if (lane == 0) atomicAdd(&corr[i], fexp2(d));   // A pre-scaled
    }
    __syncthreads();

    // per-row loss contribution: ln(rowsum - corr) - diag
    float v = 0.f;
    for (int i = threadIdx.x; i < m; i += 256) {
        const int r = rows[i];
        v += log2f(rowsum[r] - corr[i]) * LN2F - diag[r];
    }
    #pragma unroll
    for (int o = 32; o; o >>= 1) v += __shfl_xor(v, o);
    if (lane == 0) wred[wave] = v;
    __syncthreads();
    if (threadIdx.x == 0)
        atomicAdd(acc, wred[0] + wred[1] + wred[2] + wred[3]);
}

__global__ void ntx_final(const float* __restrict__ acc, float* __restrict__ out) {
    out[0] = acc[0] / (float)N;
}

extern "C" void kernel_launch(void* const* d_in, const int* in_sizes, int n_in,
                              void* d_out, int out_size, void* d_ws, size_t ws_size,
                              hipStream_t stream) {
    const float* im     = (const float*)d_in[0];
    const float* rec    = (const float*)d_in[1];
    const int*   labels = (const int*)d_in[2];
    float* out = (float*)d_out;

    unsigned short* A  = (unsigned short*)d_ws;            // 4 MB bf16 im_n * SCALE2
    unsigned short* Bm = A + (size_t)N * D;                // 4 MB bf16 rec_n (swizzled)
    float* diag   = (float*)(Bm + (size_t)N * D);          // 32 KB
    float* rowsum = diag + N;                              // 32 KB
    float* acc    = rowsum + N;                            // 4 B loss accumulator

    ntx_prep<<<N / 4, 256, 0, stream>>>(im, rec, A, Bm, diag, rowsum, acc);
    ntx_lse<<<(N / RT) * CSPLIT, 256, 0, stream>>>(A, Bm, rowsum);
    ntx_ccf<<<1024, 256, 0, stream>>>(A, Bm, labels, diag, rowsum, acc);
    ntx_final<<<1, 1, 0, stream>>>(acc, out);
}

// Round 5
// 127.839 us; speedup vs baseline: 1.1811x; 1.1811x over previous
//
#include <hip/hip_runtime.h>

#define N 8192
#define D 256
#define INV_TAU 14.285714285714286f
#define SCALE2 20.60992915555662f    // INV_TAU * log2(e)
#define LN2F 0.6931471805599453f
#define EPSN 1e-6f
#define MAXM 64                      // class-size cap (Poisson(8); P(>40) ~ 1e-16)

// fused-lse geometry
#define RT 256            // rows per block (4 waves x 64 rows)
#define CT 64             // cols per LDS tile
#define CSPLIT 16         // column splits across blocks
#define CPB (N / CSPLIT)  // 512 cols per block
#define NTILES (CPB / CT) // 8 tiles

typedef unsigned int u32x4 __attribute__((ext_vector_type(4)));
typedef __bf16 bf16x8 __attribute__((ext_vector_type(8)));
typedef float f32x4 __attribute__((ext_vector_type(4)));

__device__ inline unsigned short f2bf(float x) {
    unsigned int u = __builtin_bit_cast(unsigned int, x);
    u += 0x7fffu + ((u >> 16) & 1u);   // RNE (finite inputs)
    return (unsigned short)(u >> 16);
}
__device__ inline float b2f(unsigned short u) {
    unsigned int x = (unsigned int)u << 16;
    return __builtin_bit_cast(float, x);
}
__device__ inline float fexp2(float x) {
#if __has_builtin(__builtin_amdgcn_exp2f)
    return __builtin_amdgcn_exp2f(x);
#else
    return __expf(x * 0.6931471805599453f);
#endif
}

// One wave per row: normalize -> bf16. A rows are pre-scaled by SCALE2 so the
// GEMM epilogue is exp2(dot) with no multiply. Bm is 16B-chunk XOR-swizzled
// (chunk c of row r stored at c ^ (r&7)) so LDS fragment reads are
// conflict-free while global->LDS staging stays a linear copy. Also builds
// per-class member lists (cnt zeroed by the preceding memset).
__global__ void ntx_prep(const float* __restrict__ im, const float* __restrict__ rec,
                         const int* __restrict__ labels,
                         unsigned short* __restrict__ A, unsigned short* __restrict__ Bm,
                         float* __restrict__ diag, float* __restrict__ rowsum,
                         int* __restrict__ cnt, unsigned short* __restrict__ members) {
    const int wave = threadIdx.x >> 6;
    const int lane = threadIdx.x & 63;
    const int row  = blockIdx.x * 4 + wave;

    const float4 a = ((const float4*)(im  + (size_t)row * D))[lane];
    const float4 b = ((const float4*)(rec + (size_t)row * D))[lane];

    float ssa = a.x*a.x + a.y*a.y + a.z*a.z + a.w*a.w;
    float ssb = b.x*b.x + b.y*b.y + b.z*b.z + b.w*b.w;
    float dt  = a.x*b.x + a.y*b.y + a.z*b.z + a.w*b.w;
    #pragma unroll
    for (int o = 32; o; o >>= 1) {
        ssa += __shfl_xor(ssa, o);
        ssb += __shfl_xor(ssb, o);
        dt  += __shfl_xor(dt , o);
    }
    const float ra = SCALE2 / fmaxf(sqrtf(ssa), EPSN);   // scaled into A
    const float rb = 1.0f   / fmaxf(sqrtf(ssb), EPSN);

    ushort4 pa, pb;
    pa.x = f2bf(a.x*ra); pa.y = f2bf(a.y*ra); pa.z = f2bf(a.z*ra); pa.w = f2bf(a.w*ra);
    pb.x = f2bf(b.x*rb); pb.y = f2bf(b.y*rb); pb.z = f2bf(b.z*rb); pb.w = f2bf(b.w*rb);

    *(ushort4*)(A + (size_t)row * D + lane * 4) = pa;
    const int chunk = lane >> 1;
    const int sw = chunk ^ (row & 7);
    *(ushort4*)(Bm + (size_t)row * D + sw * 8 + (lane & 1) * 4) = pb;

    if (lane == 0) {
        diag[row]   = (dt / SCALE2) * ra * rb * INV_TAU;  // fp32 i2r[i,i], unscaled
        rowsum[row] = 0.0f;                               // ws is poisoned each launch
        const int lab = labels[row];
        const int u = atomicAdd(&cnt[lab], 1);
        if (u < MAXM) members[lab * MAXM + u] = (unsigned short)row;
    }
}

// Fused GEMM + UNMASKED sum-of-exp2 per row. 512 blocks x 256 threads.
// Double-buffered LDS: barrier drains tile t, then stage(t+1) is issued and
// its vmcnt drain overlaps the full compute of tile t.
__global__ __launch_bounds__(256, 2)
void ntx_lse(const unsigned short* __restrict__ A, const unsigned short* __restrict__ Bm,
             float* __restrict__ rowsum) {
    __shared__ __align__(16) unsigned short Bs[2][CT][D];   // 64 KB

    const int wave = threadIdx.x >> 6;
    const int lane = threadIdx.x & 63;
    const int g    = lane >> 4;
    const int n16  = lane & 15;

    const int rowblk = blockIdx.x & (N / RT - 1);   // 0..31
    const int colblk = blockIdx.x >> 5;             // 0..15
    const int row0 = rowblk * RT + wave * 64;       // this wave's 64 rows
    const int col0 = colblk * CPB;

    // A fragments: 64 rows x K=256 in registers (128 VGPRs)
    bf16x8 afrag[4][8];
    #pragma unroll
    for (int rs = 0; rs < 4; ++rs) {
        const int r = row0 + rs * 16 + n16;
        #pragma unroll
        for (int k = 0; k < 8; ++k)
            afrag[rs][k] = __builtin_bit_cast(
                bf16x8, *(const u32x4*)(A + (size_t)r * D + k * 32 + g * 8));
    }

    float acc[4][4];
    #pragma unroll
    for (int rs = 0; rs < 4; ++rs)
        #pragma unroll
        for (int q = 0; q < 4; ++q) acc[rs][q] = 0.f;

    const char* gbase = (const char*)(Bm + (size_t)col0 * D);

    // stage tile t into buffer buf (32 KB linear copy, 1 KB per instr)
    #define STAGE(t, buf)                                                          \
        {                                                                          \
            const char* gsrc = gbase + (t) * (CT * D * 2);                         \
            char* lbase = (char*)&Bs[buf][0][0];                                   \
            _Pragma("unroll")                                                      \
            for (int i = 0; i < 8; ++i) {                                          \
                const int off = (i * 4 + wave) * 1024;                             \
                __builtin_amdgcn_global_load_lds(                                  \
                    (const __attribute__((address_space(1))) void*)(gsrc + off + lane * 16), \
                    (__attribute__((address_space(3))) void*)(lbase + off),        \
                    16, 0, 0);                                                     \
            }                                                                      \
        }

    STAGE(0, 0)

    for (int t = 0; t < NTILES; ++t) {
        __syncthreads();                    // drains stage(t) (vmcnt 0 at barrier)
        if (t + 1 < NTILES) STAGE(t + 1, (t + 1) & 1)
        const int buf = t & 1;

        #pragma unroll
        for (int cs = 0; cs < 4; ++cs) {
            const int bc = cs * 16 + n16;
            bf16x8 bfrag[8];
            #pragma unroll
            for (int k = 0; k < 8; ++k)
                bfrag[k] = __builtin_bit_cast(
                    bf16x8, *(const u32x4*)(&Bs[buf][bc][((k * 4 + g) ^ (bc & 7)) * 8]));

            #pragma unroll
            for (int rs = 0; rs < 4; ++rs) {
                f32x4 c = {0.f, 0.f, 0.f, 0.f};
                #pragma unroll
                for (int k = 0; k < 8; ++k)
                    c = __builtin_amdgcn_mfma_f32_16x16x32_bf16(
                            afrag[rs][k], bfrag[k], c, 0, 0, 0);
                #pragma unroll
                for (int q = 0; q < 4; ++q)
                    acc[rs][q] += fexp2(c[q]);   // A pre-scaled: no mul, no mask
            }
        }
    }

    #pragma unroll
    for (int rs = 0; rs < 4; ++rs)
        #pragma unroll
        for (int q = 0; q < 4; ++q) {
            float v = acc[rs][q];
            v += __shfl_xor(v, 1);
            v += __shfl_xor(v, 2);
            v += __shfl_xor(v, 4);
            v += __shfl_xor(v, 8);
            if (n16 == 0)
                atomicAdd(&rowsum[row0 + rs * 16 + g * 4 + q], v);
        }
}

// One wave per ROW: subtract same-label off-diagonal exps and emit the
// fused per-row loss: loss[r] = ln(rowsum[r] - corr) - diag[r].
// Work per wave is bounded by the class size (~8 avg, ~25 max), and 8192
// waves over 1024 SIMDs hide each other's dependency chains.
__global__ void ntx_corr(const unsigned short* __restrict__ A,
                         const unsigned short* __restrict__ Bm,
                         const int* __restrict__ labels, const int* __restrict__ cnt,
                         const unsigned short* __restrict__ members,
                         const float* __restrict__ diag,
                         const float* __restrict__ rowsum,
                         float* __restrict__ loss) {
    const int wave = threadIdx.x >> 6;
    const int lane = threadIdx.x & 63;
    const int r = blockIdx.x * 4 + wave;
    const int chunk = lane >> 1;

    const int lab = labels[r];
    const int m = min(cnt[lab], MAXM);

    const ushort4 av = *(const ushort4*)(A + (size_t)r * D + lane * 4);
    const float a0 = b2f(av.x), a1 = b2f(av.y), a2 = b2f(av.z), a3 = b2f(av.w);

    float sum = 0.f;
    for (int t = 0; t < m; ++t) {
        const int j = members[lab * MAXM + t];
        if (j == r) continue;
        const int sw = chunk ^ (j & 7);   // unswizzle Bm row j
        const ushort4 bv = *(const ushort4*)(Bm + (size_t)j * D + sw * 8 + (lane & 1) * 4);
        float d = a0 * b2f(bv.x) + a1 * b2f(bv.y) + a2 * b2f(bv.z) + a3 * b2f(bv.w);
        #pragma unroll
        for (int o = 32; o; o >>= 1) d += __shfl_xor(d, o);
        sum += fexp2(d);                  // A pre-scaled
    }
    if (lane == 0)
        loss[r] = log2f(rowsum[r] - sum) * LN2F - diag[r];
}

// Single-block reduce of 8192 per-row losses.
__global__ void ntx_final(const float* __restrict__ loss, float* __restrict__ out) {
    __shared__ float red[256];
    float s = 0.f;
    for (int i = threadIdx.x; i < N; i += 256) s += loss[i];
    red[threadIdx.x] = s;
    __syncthreads();
    #pragma unroll
    for (int o = 128; o; o >>= 1) {
        if (threadIdx.x < o) red[threadIdx.x] += red[threadIdx.x + o];
        __syncthreads();
    }
    if (threadIdx.x == 0) out[0] = red[0] / (float)N;
}

extern "C" void kernel_launch(void* const* d_in, const int* in_sizes, int n_in,
                              void* d_out, int out_size, void* d_ws, size_t ws_size,
                              hipStream_t stream) {
    const float* im     = (const float*)d_in[0];
    const float* rec    = (const float*)d_in[1];
    const int*   labels = (const int*)d_in[2];
    float* out = (float*)d_out;

    unsigned short* A  = (unsigned short*)d_ws;            // 4 MB bf16 im_n * SCALE2
    unsigned short* Bm = A + (size_t)N * D;                // 4 MB bf16 rec_n (swizzled)
    float* diag   = (float*)(Bm + (size_t)N * D);          // 32 KB
    float* rowsum = diag + N;                              // 32 KB
    float* loss   = rowsum + N;                            // 32 KB
    int* cnt      = (int*)(loss + N);                      // 4 KB
    unsigned short* members = (unsigned short*)(cnt + 1024); // 128 KB

    hipMemsetAsync(cnt, 0, 1024 * sizeof(int), stream);
    ntx_prep<<<N / 4, 256, 0, stream>>>(im, rec, labels, A, Bm, diag, rowsum, cnt, members);
    ntx_lse<<<(N / RT) * CSPLIT, 256, 0, stream>>>(A, Bm, rowsum);
    ntx_corr<<<N / 4, 256, 0, stream>>>(A, Bm, labels, cnt, members, diag, rowsum, loss);
    ntx_final<<<1, 256, 0, stream>>>(loss, out);
}